// Round 13
// baseline (477.344 us; speedup 1.0000x reference)
//
#include <hip/hip_runtime.h>

// GCNDecoder: B=2, N=40000, HID=128, E=640000, IN=3, OUT=3. Float tensors f32; indices int32.
//
// Round 13 vs round 12 (429.3 us):
//   - spmm macro: direct ternary-folded expressions (r9-exact codegen for RELU=0; fused
//     max+add for RELU=1). r12's temporaries cost VGPR 40 vs 28 -> occupancy loss.
//   - gemm: W read DIRECT from global (64 KB, L2-hot across 625 blocks) - no LDS staging;
//     LDS 36.9 -> 18.4 KB (A only); epilogue 2-pass over 64-row half-tiles in same buffer.
//   - structure otherwise = round 10/12: no rA, zproj fused (MODE2), initw merged.

typedef unsigned short u16;
typedef unsigned int   u32;
typedef __bf16 bf8_t __attribute__((ext_vector_type(8)));
typedef float  f4_t  __attribute__((ext_vector_type(4)));

#define N_NODES 40000
#define N_EDGES 640000
#define BN      80000            // BATCH * N_NODES

__device__ __forceinline__ float bf2f(u16 u) {
  union { u32 i; float f; } v; v.i = ((u32)u) << 16; return v.f;
}
__device__ __forceinline__ u16 f2bf(float f) {
  union { float f; u32 i; } v; v.f = f;
  u32 i = v.i;
  return (u16)((i + 0x7FFFu + ((i >> 16) & 1u)) >> 16);   // RNE
}
__device__ __forceinline__ float asf(u32 i) {
  union { u32 u; float f; } v; v.u = i; return v.f;
}
__device__ __forceinline__ u32 pack2(float a, float b) {
  return (u32)f2bf(a) | ((u32)f2bf(b) << 16);
}
__device__ __forceinline__ float lo2f(u32 v) { return asf(v << 16); }
__device__ __forceinline__ float hi2f(u32 v) { return asf(v & 0xffff0000u); }
__device__ __forceinline__ u32 relu2(u32 v) {     // zero out negative bf16 halves (packed)
  u32 r = v;
  if (r & 0x8000u)     r &= 0xffff0000u;
  if (r & 0x80000000u) r &= 0x0000ffffu;
  return r;
}

__global__ void fill_kernel(float* __restrict__ out, int n, float v) {
  int i = blockIdx.x * 256 + threadIdx.x;
  if (i < n) out[i] = v;
}

// ---------------- CSR build (untiled, 3-phase scan) ----------------
__global__ void hist_kernel(const int* __restrict__ rows, int* __restrict__ cnt) {
  int e = blockIdx.x * 256 + threadIdx.x;
  if (e < N_EDGES) atomicAdd(&cnt[rows[e]], 1);
}

__global__ void scan1_kernel(const int* __restrict__ cnt, int* __restrict__ row_ptr,
                             int* __restrict__ blocksum) {
  __shared__ int sm[256];
  int t = threadIdx.x;
  int row = blockIdx.x * 256 + t;
  int v = (row < N_NODES) ? cnt[row] : 0;
  sm[t] = v; __syncthreads();
  for (int off = 1; off < 256; off <<= 1) {
    int u = (t >= off) ? sm[t - off] : 0;
    __syncthreads();
    sm[t] += u;
    __syncthreads();
  }
  if (row < N_NODES) row_ptr[row] = sm[t] - v;
  if (t == 255) blocksum[blockIdx.x] = sm[255];
}

__global__ void scan2_kernel(int* __restrict__ blocksum, int* __restrict__ row_ptr, int nblk) {
  __shared__ int sm[256];
  int t = threadIdx.x;
  int v = (t < nblk) ? blocksum[t] : 0;
  sm[t] = v; __syncthreads();
  for (int off = 1; off < 256; off <<= 1) {
    int u = (t >= off) ? sm[t - off] : 0;
    __syncthreads();
    sm[t] += u;
    __syncthreads();
  }
  if (t < nblk) blocksum[t] = sm[t] - v;
  if (t == 255) row_ptr[N_NODES] = sm[255];
}

__global__ void scan3_kernel(int* __restrict__ row_ptr, const int* __restrict__ blocksum,
                             int* __restrict__ cnt) {
  int row = blockIdx.x * 256 + threadIdx.x;
  if (row < N_NODES) {
    int rp = row_ptr[row] + blocksum[blockIdx.x];
    row_ptr[row] = rp;
    cnt[row] = rp;
  }
}

__global__ void scatter_kernel(const int* __restrict__ rows, const int* __restrict__ cols,
                               int* __restrict__ cur, int* __restrict__ cols_s) {
  int e = blockIdx.x * 256 + threadIdx.x;
  if (e < N_EDGES) {
    int r = rows[e];
    int pos = atomicAdd(&cur[r], 1);
    cols_s[pos] = cols[e];
  }
}

// ---------------- init (xb = p@W_init + b_init, bf16) + wprep, one launch ----------------
__global__ void initw_kernel(const float* __restrict__ p, const float* __restrict__ W,
                             const float* __restrict__ bias, u16* __restrict__ xb,
                             const float* __restrict__ Wf_b, const float* __restrict__ Ws_b,
                             const float* __restrict__ bf_b, const float* __restrict__ bs_b,
                             u16* __restrict__ WtCat, float* __restrict__ biasCat) {
  if (blockIdx.x >= 20000) {                     // wprep part: 512 blocks
    int idx = (blockIdx.x - 20000) * 256 + threadIdx.x;   // 4*128*256 = 131072
    int g = idx >> 15, rem = idx & 32767;
    int h = rem >> 8, k = rem & 255;
    float v = (k < 128) ? Ws_b[(g * 128 + k) * 128 + h]
                        : Wf_b[(g * 128 + (k - 128)) * 128 + h];
    WtCat[idx] = f2bf(v);
    if (k == 0) biasCat[g * 128 + h] = bs_b[g * 128 + h] + bf_b[g * 128 + h];
    return;
  }
  int idx = blockIdx.x * 256 + threadIdx.x;      // BN*64 = 5,120,000
  int row = idx >> 6;
  int h = (idx & 63) * 2;
  float p0 = p[row * 3], p1 = p[row * 3 + 1], p2 = p[row * 3 + 2];
  float s0 = p0 * W[h]     + p1 * W[128 + h]     + p2 * W[256 + h]     + bias[h];
  float s1 = p0 * W[h + 1] + p1 * W[128 + h + 1] + p2 * W[256 + h + 1] + bias[h + 1];
  ((u32*)xb)[(size_t)row * 64 + (h >> 1)] = pack2(s0, s1);
}

// ---------------- gather SPMM: y[b][r][:] = (1/deg) * sum_e fin(x[b][col[e]][:]) ----------------
// r9-exact codegen: direct += expressions, ternary folds at compile time.
#define ACC8R(u, A0, A1, A2, A3, A4, A5, A6, A7)                               \
  A0 += RELU ? fmaxf(lo2f((u).x), 0.f) : lo2f((u).x);                          \
  A1 += RELU ? fmaxf(hi2f((u).x), 0.f) : hi2f((u).x);                          \
  A2 += RELU ? fmaxf(lo2f((u).y), 0.f) : lo2f((u).y);                          \
  A3 += RELU ? fmaxf(hi2f((u).y), 0.f) : hi2f((u).y);                          \
  A4 += RELU ? fmaxf(lo2f((u).z), 0.f) : lo2f((u).z);                          \
  A5 += RELU ? fmaxf(hi2f((u).z), 0.f) : hi2f((u).z);                          \
  A6 += RELU ? fmaxf(lo2f((u).w), 0.f) : lo2f((u).w);                          \
  A7 += RELU ? fmaxf(hi2f((u).w), 0.f) : hi2f((u).w);

template <int RELU>
__global__ void spmm_kernel(const int* __restrict__ row_ptr, const int* __restrict__ cols_s,
                            const u16* __restrict__ xin, u16* __restrict__ yout) {
  int row = blockIdx.x * 4 + (threadIdx.x >> 6);
  int l = threadIdx.x & 63;
  int g = l >> 4, sl = l & 15;
  int s = row_ptr[row], e = row_ptr[row + 1];
  const uint4* X0 = (const uint4*)xin + sl;
  const uint4* X1 = X0 + 640000;
  float a0 = 0.f, a1 = 0.f, a2 = 0.f, a3 = 0.f, a4 = 0.f, a5 = 0.f, a6 = 0.f, a7 = 0.f;
  float b0 = 0.f, b1 = 0.f, b2 = 0.f, b3 = 0.f, b4 = 0.f, b5 = 0.f, b6 = 0.f, b7 = 0.f;
  int i = s;
  for (; i + 7 < e; i += 8) {                    // 4 uint4 loads in flight
    int c0 = cols_s[i + g], c1 = cols_s[i + 4 + g];
    uint4 u00 = X0[(size_t)c0 * 16];
    uint4 u01 = X1[(size_t)c0 * 16];
    uint4 u10 = X0[(size_t)c1 * 16];
    uint4 u11 = X1[(size_t)c1 * 16];
    ACC8R(u00, a0, a1, a2, a3, a4, a5, a6, a7);
    ACC8R(u01, b0, b1, b2, b3, b4, b5, b6, b7);
    ACC8R(u10, a0, a1, a2, a3, a4, a5, a6, a7);
    ACC8R(u11, b0, b1, b2, b3, b4, b5, b6, b7);
  }
  for (; i + 3 < e; i += 4) {
    int c = cols_s[i + g];
    uint4 u0 = X0[(size_t)c * 16];
    uint4 u1 = X1[(size_t)c * 16];
    ACC8R(u0, a0, a1, a2, a3, a4, a5, a6, a7);
    ACC8R(u1, b0, b1, b2, b3, b4, b5, b6, b7);
  }
  if (i + g < e) {
    int c = cols_s[i + g];
    uint4 u0 = X0[(size_t)c * 16];
    uint4 u1 = X1[(size_t)c * 16];
    ACC8R(u0, a0, a1, a2, a3, a4, a5, a6, a7);
    ACC8R(u1, b0, b1, b2, b3, b4, b5, b6, b7);
  }
  // cross-subgroup butterfly (4 subgroups -> 2 steps), both batches
  a0 += __shfl_xor(a0, 16); a1 += __shfl_xor(a1, 16); a2 += __shfl_xor(a2, 16); a3 += __shfl_xor(a3, 16);
  a4 += __shfl_xor(a4, 16); a5 += __shfl_xor(a5, 16); a6 += __shfl_xor(a6, 16); a7 += __shfl_xor(a7, 16);
  b0 += __shfl_xor(b0, 16); b1 += __shfl_xor(b1, 16); b2 += __shfl_xor(b2, 16); b3 += __shfl_xor(b3, 16);
  b4 += __shfl_xor(b4, 16); b5 += __shfl_xor(b5, 16); b6 += __shfl_xor(b6, 16); b7 += __shfl_xor(b7, 16);
  a0 += __shfl_xor(a0, 32); a1 += __shfl_xor(a1, 32); a2 += __shfl_xor(a2, 32); a3 += __shfl_xor(a3, 32);
  a4 += __shfl_xor(a4, 32); a5 += __shfl_xor(a5, 32); a6 += __shfl_xor(a6, 32); a7 += __shfl_xor(a7, 32);
  b0 += __shfl_xor(b0, 32); b1 += __shfl_xor(b1, 32); b2 += __shfl_xor(b2, 32); b3 += __shfl_xor(b3, 32);
  b4 += __shfl_xor(b4, 32); b5 += __shfl_xor(b5, 32); b6 += __shfl_xor(b6, 32); b7 += __shfl_xor(b7, 32);
  float sc = (e > s) ? 1.f / (float)(e - s) : 0.f;
  if (g == 0) {
    uint4 o;
    o.x = pack2(a0 * sc, a1 * sc);
    o.y = pack2(a2 * sc, a3 * sc);
    o.z = pack2(a4 * sc, a5 * sc);
    o.w = pack2(a6 * sc, a7 * sc);
    *((uint4*)yout + (size_t)row * 16 + sl) = o;
  } else if (g == 1) {
    uint4 o;
    o.x = pack2(b0 * sc, b1 * sc);
    o.y = pack2(b2 * sc, b3 * sc);
    o.z = pack2(b4 * sc, b5 * sc);
    o.w = pack2(b6 * sc, b7 * sc);
    *((uint4*)yout + 640000 + (size_t)row * 16 + sl) = o;
  }
}

// ---------------- fused gconv GEMM: [fin(rin) | y] (M x 256) @ WtCat[g]^T (256 x 128) + bias ----
// W direct from global (L2-hot); LDS stages A only; 2-pass epilogue over 64-row half-tiles.
// MODE 0: A-half = relu(rin) in staging; rout = relu(acc+bias)                 (rin = xb)
// MODE 1: A-half = rin as-is (rB); xb += acc+bias, write xb only
// MODE 2: MODE 1 + fused zproj (zf/zs from fp32 xb+dx), NO xb write (dead after)
#define TS 136                                   // epilogue tile row stride (u16)
template <int MODE>
__global__ __launch_bounds__(256, 4) void gemm_kernel(
    const u16* __restrict__ rin, const u16* __restrict__ yin,
    const u16* __restrict__ WtCat, const float* __restrict__ biasCat, int g,
    u16* __restrict__ rout, u16* __restrict__ xresid,
    float4* __restrict__ zf4, float4* __restrict__ zs4,
    const float* __restrict__ Wfo, const float* __restrict__ Wso,
    const float* __restrict__ bfo, const float* __restrict__ bso) {
  __shared__ __align__(16) u16 lds[9216];        // 18,432 B: A staging (128x72); epi half 64*TS=8704
  int tid = threadIdx.x;
  int m0 = blockIdx.x * 128;
  int li = tid & 15, q = (tid >> 4) & 3, wv = tid >> 6;
  int wmo = (wv >> 1) * 64, wno = (wv & 1) * 64;

  f4_t acc[4][4];
#pragma unroll
  for (int i = 0; i < 4; ++i)
#pragma unroll
    for (int j = 0; j < 4; ++j) acc[i][j] = (f4_t){0.f, 0.f, 0.f, 0.f};

  const u16* Wsrc = WtCat + (size_t)g * 32768;

  for (int kb = 0; kb < 256; kb += 64) {
    __syncthreads();
    const u16* srcA = (kb < 128) ? (rin + kb) : (yin + (kb - 128));
#pragma unroll
    for (int p2 = 0; p2 < 4; ++p2) {
      int idx = p2 * 256 + tid;                  // 0..1023, A only
      int row = idx >> 3, seg = idx & 7;
      uint4 va = *reinterpret_cast<const uint4*>(srcA + (size_t)(m0 + row) * 128 + seg * 8);
      if (MODE == 0 && kb < 128) {               // relu-on-read of xb
        va.x = relu2(va.x); va.y = relu2(va.y); va.z = relu2(va.z); va.w = relu2(va.w);
      }
      *reinterpret_cast<uint4*>(&lds[row * 72 + seg * 8]) = va;
    }
    __syncthreads();
#pragma unroll
    for (int kk = 0; kk < 64; kk += 32) {
      bf8_t af[4], wf[4];
#pragma unroll
      for (int t = 0; t < 4; ++t)
        af[t] = __builtin_bit_cast(bf8_t,
            *reinterpret_cast<const uint4*>(&lds[(wmo + t * 16 + li) * 72 + kk + q * 8]));
#pragma unroll
      for (int t = 0; t < 4; ++t)                // W direct from global (L2-hot)
        wf[t] = __builtin_bit_cast(bf8_t, *reinterpret_cast<const uint4*>(
            Wsrc + (size_t)(wno + t * 16 + li) * 256 + kb + kk + q * 8));
#pragma unroll
      for (int i = 0; i < 4; ++i)
#pragma unroll
        for (int j = 0; j < 4; ++j)
          acc[i][j] = __builtin_amdgcn_mfma_f32_16x16x32_bf16(af[i], wf[j], acc[i][j], 0, 0, 0);
    }
  }

  float bias[4];
#pragma unroll
  for (int j = 0; j < 4; ++j) bias[j] = biasCat[g * 128 + wno + j * 16 + li];

  // epilogue weights for MODE2 (thread-invariant: ch = tid&15)
  float wzf[8][3], wzs[8][3];
  if (MODE == 2) {
    int chb = (tid & 15) * 8;
#pragma unroll
    for (int c = 0; c < 8; ++c)
#pragma unroll
      for (int d = 0; d < 3; ++d) {
        wzf[c][d] = Wfo[(chb + c) * 3 + d];
        wzs[c][d] = Wso[(chb + c) * 3 + d];
      }
  }

  // ---- 2-pass epilogue: rows [0,64) then [64,128) through the 18.4 KB buffer ----
#pragma unroll
  for (int half = 0; half < 2; ++half) {
    __syncthreads();                             // previous LDS readers done
    if (wmo == half * 64) {
#pragma unroll
      for (int i = 0; i < 4; ++i)
#pragma unroll
        for (int j = 0; j < 4; ++j)
#pragma unroll
          for (int r2 = 0; r2 < 4; ++r2) {
            int m = i * 16 + q * 4 + r2;         // 0..63 local
            lds[m * TS + wno + j * 16 + li] = f2bf(acc[i][j][r2] + bias[j]);
          }
    }
    __syncthreads();
    // coalesced IO: 1024 uint4 chunks (64 rows x 16)
#pragma unroll
    for (int p2 = 0; p2 < 4; ++p2) {
      int idx = p2 * 256 + tid;
      int row = idx >> 4, ch = idx & 15;
      uint4 cv = *reinterpret_cast<const uint4*>(&lds[row * TS + ch * 8]);
      size_t gid = (size_t)(m0 + half * 64 + row) * 16 + ch;
      if (MODE == 0) {
        uint4 o;
        o.x = relu2(cv.x); o.y = relu2(cv.y); o.z = relu2(cv.z); o.w = relu2(cv.w);
        ((uint4*)rout)[gid] = o;
      } else if (MODE == 1) {
        uint4 xv = ((const uint4*)xresid)[gid];
        uint4 nx;
        float x0, x1;
        x0 = lo2f(xv.x) + lo2f(cv.x); x1 = hi2f(xv.x) + hi2f(cv.x); nx.x = pack2(x0, x1);
        x0 = lo2f(xv.y) + lo2f(cv.y); x1 = hi2f(xv.y) + hi2f(cv.y); nx.y = pack2(x0, x1);
        x0 = lo2f(xv.z) + lo2f(cv.z); x1 = hi2f(xv.z) + hi2f(cv.z); nx.z = pack2(x0, x1);
        x0 = lo2f(xv.w) + lo2f(cv.w); x1 = hi2f(xv.w) + hi2f(cv.w); nx.w = pack2(x0, x1);
        ((uint4*)xresid)[gid] = nx;
      } else {                                   // MODE 2: fused zproj, no xb write
        uint4 xv = ((const uint4*)xresid)[gid];
        float zf0 = 0.f, zf1 = 0.f, zf2 = 0.f, zs0 = 0.f, zs1 = 0.f, zs2 = 0.f;
#pragma unroll
        for (int q2 = 0; q2 < 4; ++q2) {
          u32 xu = ((const u32*)&xv)[q2], cu = ((const u32*)&cv)[q2];
          float r0 = fmaxf(lo2f(xu) + lo2f(cu), 0.f);
          float r1 = fmaxf(hi2f(xu) + hi2f(cu), 0.f);
          int c = 2 * q2;
          zf0 += r0 * wzf[c][0] + r1 * wzf[c + 1][0];
          zf1 += r0 * wzf[c][1] + r1 * wzf[c + 1][1];
          zf2 += r0 * wzf[c][2] + r1 * wzf[c + 1][2];
          zs0 += r0 * wzs[c][0] + r1 * wzs[c + 1][0];
          zs1 += r0 * wzs[c][1] + r1 * wzs[c + 1][1];
          zs2 += r0 * wzs[c][2] + r1 * wzs[c + 1][2];
        }
#pragma unroll
        for (int off = 1; off < 16; off <<= 1) {
          zf0 += __shfl_xor(zf0, off); zf1 += __shfl_xor(zf1, off); zf2 += __shfl_xor(zf2, off);
          zs0 += __shfl_xor(zs0, off); zs1 += __shfl_xor(zs1, off); zs2 += __shfl_xor(zs2, off);
        }
        if ((tid & 15) == 0) {
          int m = m0 + half * 64 + row;
          zf4[m] = make_float4(zf0, zf1, zf2, 0.f);
          zs4[m] = make_float4(zs0 + bso[0] + bfo[0], zs1 + bso[1] + bfo[1],
                               zs2 + bso[2] + bfo[2], 0.f);
        }
      }
    }
  }
}

// ---------------- 3-channel spmm + add ----------------
__global__ void spmm3_kernel(const int* __restrict__ row_ptr, const int* __restrict__ cols_s,
                             const float4* __restrict__ zf4, const float4* __restrict__ zs4,
                             float* __restrict__ out) {
  int idx = blockIdx.x * 256 + threadIdx.x;
  if (idx >= BN) return;
  int b = (idx >= N_NODES) ? 1 : 0;
  int r = idx - b * N_NODES;
  int s = row_ptr[r], e = row_ptr[r + 1];
  const float4* Z = zf4 + (size_t)b * N_NODES;
  float a0 = 0.f, a1 = 0.f, a2 = 0.f;
  for (int i = s; i < e; ++i) {
    float4 z = Z[cols_s[i]];
    a0 += z.x; a1 += z.y; a2 += z.z;
  }
  float sc = (e > s) ? 1.f / (float)(e - s) : 0.f;
  float4 zs = zs4[idx];
  out[idx * 3 + 0] = zs.x + a0 * sc;
  out[idx * 3 + 1] = zs.y + a1 * sc;
  out[idx * 3 + 2] = zs.z + a2 * sc;
}

extern "C" void kernel_launch(void* const* d_in, const int* in_sizes, int n_in,
                              void* d_out, int out_size, void* d_ws, size_t ws_size,
                              hipStream_t stream) {
  float* out = (float*)d_out;
  int fill_grid = (out_size + 255) / 256;

  const int exp_sizes[14] = {240000, 640000, 640000, 640000, 384, 128,
                             65536, 512, 65536, 512, 384, 3, 384, 3};
  bool sizes_ok = (n_in == 14);
  if (sizes_ok) for (int i = 0; i < 14; ++i) if (in_sizes[i] != exp_sizes[i]) sizes_ok = false;
  if (!sizes_ok) {
    fill_kernel<<<fill_grid, 256, 0, stream>>>(out, out_size, 1.0f);
    return;
  }

  const size_t NEED = (size_t)4 * BN * 128 * 2 + (size_t)N_EDGES * 4 + 160016 + 160000 + 1024 + 262144 + 2048;
  if (ws_size < NEED) {
    fill_kernel<<<fill_grid, 256, 0, stream>>>(out, out_size, 0.0f);
    return;
  }

  const float* p      = (const float*)d_in[0];
  const int*   erows  = (const int*)d_in[2];
  const int*   ecols  = (const int*)d_in[3];
  const float* W_init = (const float*)d_in[4];
  const float* b_init = (const float*)d_in[5];
  const float* Wf_b   = (const float*)d_in[6];
  const float* bf_b   = (const float*)d_in[7];
  const float* Ws_b   = (const float*)d_in[8];
  const float* bs_b   = (const float*)d_in[9];
  const float* Wf_o   = (const float*)d_in[10];
  const float* bf_o   = (const float*)d_in[11];
  const float* Ws_o   = (const float*)d_in[12];
  const float* bs_o   = (const float*)d_in[13];

  char* w = (char*)d_ws;
  char*  zbuf     = w;         w += (size_t)BN * 128 * 2;       // holds zf4/zs4
  u16*   rB       = (u16*)w;   w += (size_t)BN * 128 * 2;
  u16*   y        = (u16*)w;   w += (size_t)BN * 128 * 2;
  u16*   xb       = (u16*)w;   w += (size_t)BN * 128 * 2;
  int*   cols_s   = (int*)w;   w += (size_t)N_EDGES * 4;
  int*   row_ptr  = (int*)w;   w += 160016;
  int*   cnt      = (int*)w;   w += 160000;
  int*   blocksum = (int*)w;   w += 1024;
  u16*   WtCat    = (u16*)w;   w += 4 * 128 * 256 * 2;
  float* biasCat  = (float*)w; w += 4 * 128 * 4;

  float4* zf4 = (float4*)zbuf;                                  // 1,280,000 B
  float4* zs4 = (float4*)(zbuf + 1280000);                      // 1,280,000 B

  const int NBLK = (N_NODES + 255) / 256;                       // 157

  hipMemsetAsync(cnt, 0, N_NODES * 4, stream);
  hist_kernel<<<2500, 256, 0, stream>>>(erows, cnt);
  scan1_kernel<<<NBLK, 256, 0, stream>>>(cnt, row_ptr, blocksum);
  scan2_kernel<<<1, 256, 0, stream>>>(blocksum, row_ptr, NBLK);
  scan3_kernel<<<NBLK, 256, 0, stream>>>(row_ptr, blocksum, cnt);
  scatter_kernel<<<2500, 256, 0, stream>>>(erows, ecols, cnt, cols_s);
  initw_kernel<<<20512, 256, 0, stream>>>(p, W_init, b_init, xb,
                                          Wf_b, Ws_b, bf_b, bs_b, WtCat, biasCat);

  for (int blk = 0; blk < 2; ++blk) {
    spmm_kernel<1><<<10000, 256, 0, stream>>>(row_ptr, cols_s, xb, y);
    gemm_kernel<0><<<625, 256, 0, stream>>>(xb, y, WtCat, biasCat, 2 * blk, rB, nullptr,
                                            nullptr, nullptr, nullptr, nullptr, nullptr, nullptr);
    spmm_kernel<0><<<10000, 256, 0, stream>>>(row_ptr, cols_s, rB, y);
    if (blk == 0)
      gemm_kernel<1><<<625, 256, 0, stream>>>(rB, y, WtCat, biasCat, 1, nullptr, xb,
                                              nullptr, nullptr, nullptr, nullptr, nullptr, nullptr);
    else
      gemm_kernel<2><<<625, 256, 0, stream>>>(rB, y, WtCat, biasCat, 3, nullptr, xb,
                                              zf4, zs4, Wf_o, Ws_o, bf_o, bs_o);
  }
  spmm3_kernel<<<(BN + 255) / 256, 256, 0, stream>>>(row_ptr, cols_s, zf4, zs4, out);
}

// Round 14
// 428.326 us; speedup vs baseline: 1.1144x; 1.1144x over previous
//
#include <hip/hip_runtime.h>

// GCNDecoder: B=2, N=40000, HID=128, E=640000, IN=3, OUT=3. Float tensors f32; indices int32.
//
// Round 14 = round-12 gemm (W staged in LDS — r13's direct-global W regressed 28->56 us:
// uncoalesced 16B/lane stride-512B loads inside the MFMA loop; LDS amortizes one coalesced
// read across 4 waves x 8 k-steps) + r13 spmm ternary macro (isolated codegen experiment).
//   - structure = round 10/12: no rA (relu-on-read), zproj fused (MODE2), initw merged.

typedef unsigned short u16;
typedef unsigned int   u32;
typedef __bf16 bf8_t __attribute__((ext_vector_type(8)));
typedef float  f4_t  __attribute__((ext_vector_type(4)));

#define N_NODES 40000
#define N_EDGES 640000
#define BN      80000            // BATCH * N_NODES

__device__ __forceinline__ float bf2f(u16 u) {
  union { u32 i; float f; } v; v.i = ((u32)u) << 16; return v.f;
}
__device__ __forceinline__ u16 f2bf(float f) {
  union { float f; u32 i; } v; v.f = f;
  u32 i = v.i;
  return (u16)((i + 0x7FFFu + ((i >> 16) & 1u)) >> 16);   // RNE
}
__device__ __forceinline__ float asf(u32 i) {
  union { u32 u; float f; } v; v.u = i; return v.f;
}
__device__ __forceinline__ u32 pack2(float a, float b) {
  return (u32)f2bf(a) | ((u32)f2bf(b) << 16);
}
__device__ __forceinline__ float lo2f(u32 v) { return asf(v << 16); }
__device__ __forceinline__ float hi2f(u32 v) { return asf(v & 0xffff0000u); }
__device__ __forceinline__ u32 relu2(u32 v) {     // zero out negative bf16 halves (packed)
  u32 r = v;
  if (r & 0x8000u)     r &= 0xffff0000u;
  if (r & 0x80000000u) r &= 0x0000ffffu;
  return r;
}

__global__ void fill_kernel(float* __restrict__ out, int n, float v) {
  int i = blockIdx.x * 256 + threadIdx.x;
  if (i < n) out[i] = v;
}

// ---------------- CSR build (untiled, 3-phase scan) ----------------
__global__ void hist_kernel(const int* __restrict__ rows, int* __restrict__ cnt) {
  int e = blockIdx.x * 256 + threadIdx.x;
  if (e < N_EDGES) atomicAdd(&cnt[rows[e]], 1);
}

__global__ void scan1_kernel(const int* __restrict__ cnt, int* __restrict__ row_ptr,
                             int* __restrict__ blocksum) {
  __shared__ int sm[256];
  int t = threadIdx.x;
  int row = blockIdx.x * 256 + t;
  int v = (row < N_NODES) ? cnt[row] : 0;
  sm[t] = v; __syncthreads();
  for (int off = 1; off < 256; off <<= 1) {
    int u = (t >= off) ? sm[t - off] : 0;
    __syncthreads();
    sm[t] += u;
    __syncthreads();
  }
  if (row < N_NODES) row_ptr[row] = sm[t] - v;
  if (t == 255) blocksum[blockIdx.x] = sm[255];
}

__global__ void scan2_kernel(int* __restrict__ blocksum, int* __restrict__ row_ptr, int nblk) {
  __shared__ int sm[256];
  int t = threadIdx.x;
  int v = (t < nblk) ? blocksum[t] : 0;
  sm[t] = v; __syncthreads();
  for (int off = 1; off < 256; off <<= 1) {
    int u = (t >= off) ? sm[t - off] : 0;
    __syncthreads();
    sm[t] += u;
    __syncthreads();
  }
  if (t < nblk) blocksum[t] = sm[t] - v;
  if (t == 255) row_ptr[N_NODES] = sm[255];
}

__global__ void scan3_kernel(int* __restrict__ row_ptr, const int* __restrict__ blocksum,
                             int* __restrict__ cnt) {
  int row = blockIdx.x * 256 + threadIdx.x;
  if (row < N_NODES) {
    int rp = row_ptr[row] + blocksum[blockIdx.x];
    row_ptr[row] = rp;
    cnt[row] = rp;
  }
}

__global__ void scatter_kernel(const int* __restrict__ rows, const int* __restrict__ cols,
                               int* __restrict__ cur, int* __restrict__ cols_s) {
  int e = blockIdx.x * 256 + threadIdx.x;
  if (e < N_EDGES) {
    int r = rows[e];
    int pos = atomicAdd(&cur[r], 1);
    cols_s[pos] = cols[e];
  }
}

// ---------------- init (xb = p@W_init + b_init, bf16) + wprep, one launch ----------------
__global__ void initw_kernel(const float* __restrict__ p, const float* __restrict__ W,
                             const float* __restrict__ bias, u16* __restrict__ xb,
                             const float* __restrict__ Wf_b, const float* __restrict__ Ws_b,
                             const float* __restrict__ bf_b, const float* __restrict__ bs_b,
                             u16* __restrict__ WtCat, float* __restrict__ biasCat) {
  if (blockIdx.x >= 20000) {                     // wprep part: 512 blocks
    int idx = (blockIdx.x - 20000) * 256 + threadIdx.x;   // 4*128*256 = 131072
    int g = idx >> 15, rem = idx & 32767;
    int h = rem >> 8, k = rem & 255;
    float v = (k < 128) ? Ws_b[(g * 128 + k) * 128 + h]
                        : Wf_b[(g * 128 + (k - 128)) * 128 + h];
    WtCat[idx] = f2bf(v);
    if (k == 0) biasCat[g * 128 + h] = bs_b[g * 128 + h] + bf_b[g * 128 + h];
    return;
  }
  int idx = blockIdx.x * 256 + threadIdx.x;      // BN*64 = 5,120,000
  int row = idx >> 6;
  int h = (idx & 63) * 2;
  float p0 = p[row * 3], p1 = p[row * 3 + 1], p2 = p[row * 3 + 2];
  float s0 = p0 * W[h]     + p1 * W[128 + h]     + p2 * W[256 + h]     + bias[h];
  float s1 = p0 * W[h + 1] + p1 * W[128 + h + 1] + p2 * W[256 + h + 1] + bias[h + 1];
  ((u32*)xb)[(size_t)row * 64 + (h >> 1)] = pack2(s0, s1);
}

// ---------------- gather SPMM: y[b][r][:] = (1/deg) * sum_e fin(x[b][col[e]][:]) ----------------
// r9-shape loop; direct ternary-folded += expressions (minimal VGPR).
#define ACC8R(u, A0, A1, A2, A3, A4, A5, A6, A7)                               \
  A0 += RELU ? fmaxf(lo2f((u).x), 0.f) : lo2f((u).x);                          \
  A1 += RELU ? fmaxf(hi2f((u).x), 0.f) : hi2f((u).x);                          \
  A2 += RELU ? fmaxf(lo2f((u).y), 0.f) : lo2f((u).y);                          \
  A3 += RELU ? fmaxf(hi2f((u).y), 0.f) : hi2f((u).y);                          \
  A4 += RELU ? fmaxf(lo2f((u).z), 0.f) : lo2f((u).z);                          \
  A5 += RELU ? fmaxf(hi2f((u).z), 0.f) : hi2f((u).z);                          \
  A6 += RELU ? fmaxf(lo2f((u).w), 0.f) : lo2f((u).w);                          \
  A7 += RELU ? fmaxf(hi2f((u).w), 0.f) : hi2f((u).w);

template <int RELU>
__global__ void spmm_kernel(const int* __restrict__ row_ptr, const int* __restrict__ cols_s,
                            const u16* __restrict__ xin, u16* __restrict__ yout) {
  int row = blockIdx.x * 4 + (threadIdx.x >> 6);
  int l = threadIdx.x & 63;
  int g = l >> 4, sl = l & 15;
  int s = row_ptr[row], e = row_ptr[row + 1];
  const uint4* X0 = (const uint4*)xin + sl;
  const uint4* X1 = X0 + 640000;
  float a0 = 0.f, a1 = 0.f, a2 = 0.f, a3 = 0.f, a4 = 0.f, a5 = 0.f, a6 = 0.f, a7 = 0.f;
  float b0 = 0.f, b1 = 0.f, b2 = 0.f, b3 = 0.f, b4 = 0.f, b5 = 0.f, b6 = 0.f, b7 = 0.f;
  int i = s;
  for (; i + 7 < e; i += 8) {                    // 4 uint4 loads in flight
    int c0 = cols_s[i + g], c1 = cols_s[i + 4 + g];
    uint4 u00 = X0[(size_t)c0 * 16];
    uint4 u01 = X1[(size_t)c0 * 16];
    uint4 u10 = X0[(size_t)c1 * 16];
    uint4 u11 = X1[(size_t)c1 * 16];
    ACC8R(u00, a0, a1, a2, a3, a4, a5, a6, a7);
    ACC8R(u01, b0, b1, b2, b3, b4, b5, b6, b7);
    ACC8R(u10, a0, a1, a2, a3, a4, a5, a6, a7);
    ACC8R(u11, b0, b1, b2, b3, b4, b5, b6, b7);
  }
  for (; i + 3 < e; i += 4) {
    int c = cols_s[i + g];
    uint4 u0 = X0[(size_t)c * 16];
    uint4 u1 = X1[(size_t)c * 16];
    ACC8R(u0, a0, a1, a2, a3, a4, a5, a6, a7);
    ACC8R(u1, b0, b1, b2, b3, b4, b5, b6, b7);
  }
  if (i + g < e) {
    int c = cols_s[i + g];
    uint4 u0 = X0[(size_t)c * 16];
    uint4 u1 = X1[(size_t)c * 16];
    ACC8R(u0, a0, a1, a2, a3, a4, a5, a6, a7);
    ACC8R(u1, b0, b1, b2, b3, b4, b5, b6, b7);
  }
  // cross-subgroup butterfly (4 subgroups -> 2 steps), both batches
  a0 += __shfl_xor(a0, 16); a1 += __shfl_xor(a1, 16); a2 += __shfl_xor(a2, 16); a3 += __shfl_xor(a3, 16);
  a4 += __shfl_xor(a4, 16); a5 += __shfl_xor(a5, 16); a6 += __shfl_xor(a6, 16); a7 += __shfl_xor(a7, 16);
  b0 += __shfl_xor(b0, 16); b1 += __shfl_xor(b1, 16); b2 += __shfl_xor(b2, 16); b3 += __shfl_xor(b3, 16);
  b4 += __shfl_xor(b4, 16); b5 += __shfl_xor(b5, 16); b6 += __shfl_xor(b6, 16); b7 += __shfl_xor(b7, 16);
  a0 += __shfl_xor(a0, 32); a1 += __shfl_xor(a1, 32); a2 += __shfl_xor(a2, 32); a3 += __shfl_xor(a3, 32);
  a4 += __shfl_xor(a4, 32); a5 += __shfl_xor(a5, 32); a6 += __shfl_xor(a6, 32); a7 += __shfl_xor(a7, 32);
  b0 += __shfl_xor(b0, 32); b1 += __shfl_xor(b1, 32); b2 += __shfl_xor(b2, 32); b3 += __shfl_xor(b3, 32);
  b4 += __shfl_xor(b4, 32); b5 += __shfl_xor(b5, 32); b6 += __shfl_xor(b6, 32); b7 += __shfl_xor(b7, 32);
  float sc = (e > s) ? 1.f / (float)(e - s) : 0.f;
  if (g == 0) {
    uint4 o;
    o.x = pack2(a0 * sc, a1 * sc);
    o.y = pack2(a2 * sc, a3 * sc);
    o.z = pack2(a4 * sc, a5 * sc);
    o.w = pack2(a6 * sc, a7 * sc);
    *((uint4*)yout + (size_t)row * 16 + sl) = o;
  } else if (g == 1) {
    uint4 o;
    o.x = pack2(b0 * sc, b1 * sc);
    o.y = pack2(b2 * sc, b3 * sc);
    o.z = pack2(b4 * sc, b5 * sc);
    o.w = pack2(b6 * sc, b7 * sc);
    *((uint4*)yout + 640000 + (size_t)row * 16 + sl) = o;
  }
}

// ---------------- fused gconv GEMM: [fin(rin) | y] (M x 256) @ WtCat[g]^T (256 x 128) + bias ----
// Round-12 exact body: A and W staged in LDS, single-pass TS=136 epilogue.
// MODE 0: A-half = relu(rin) in staging; rout = relu(acc+bias)                 (rin = xb)
// MODE 1: A-half = rin as-is (rB); xb += acc+bias, write xb only
// MODE 2: MODE 1 + fused zproj (zf/zs from fp32 xb+dx), NO xb write (dead after)
#define TS 136                                   // tile row stride (u16); 272 B, 16B-aligned
template <int MODE>
__global__ __launch_bounds__(256, 4) void gemm_kernel(
    const u16* __restrict__ rin, const u16* __restrict__ yin,
    const u16* __restrict__ WtCat, const float* __restrict__ biasCat, int g,
    u16* __restrict__ rout, u16* __restrict__ xresid,
    float4* __restrict__ zf4, float4* __restrict__ zs4,
    const float* __restrict__ Wfo, const float* __restrict__ Wso,
    const float* __restrict__ bfo, const float* __restrict__ bso) {
  __shared__ __align__(16) u16 lds[18432];       // 36,864 B: ldsA[0..9215], ldsW[9216..]; epi tile 128*TS
  u16* ldsW = lds + 9216;
  int tid = threadIdx.x;
  int m0 = blockIdx.x * 128;
  int li = tid & 15, q = (tid >> 4) & 3, wv = tid >> 6;
  int wmo = (wv >> 1) * 64, wno = (wv & 1) * 64;

  f4_t acc[4][4];
#pragma unroll
  for (int i = 0; i < 4; ++i)
#pragma unroll
    for (int j = 0; j < 4; ++j) acc[i][j] = (f4_t){0.f, 0.f, 0.f, 0.f};

  const u16* Wsrc = WtCat + (size_t)g * 32768;

  for (int kb = 0; kb < 256; kb += 64) {
    __syncthreads();
    const u16* srcA = (kb < 128) ? (rin + kb) : (yin + (kb - 128));
#pragma unroll
    for (int p2 = 0; p2 < 4; ++p2) {
      int idx = p2 * 256 + tid;                  // 0..1023
      int row = idx >> 3, seg = idx & 7;
      uint4 va = *reinterpret_cast<const uint4*>(srcA + (size_t)(m0 + row) * 128 + seg * 8);
      if (MODE == 0 && kb < 128) {               // relu-on-read of xb
        va.x = relu2(va.x); va.y = relu2(va.y); va.z = relu2(va.z); va.w = relu2(va.w);
      }
      *reinterpret_cast<uint4*>(&lds[row * 72 + seg * 8]) = va;
      uint4 vw = *reinterpret_cast<const uint4*>(Wsrc + (size_t)row * 256 + kb + seg * 8);
      *reinterpret_cast<uint4*>(&ldsW[row * 72 + seg * 8]) = vw;
    }
    __syncthreads();
#pragma unroll
    for (int kk = 0; kk < 64; kk += 32) {
      bf8_t af[4], wf[4];
#pragma unroll
      for (int t = 0; t < 4; ++t)
        af[t] = __builtin_bit_cast(bf8_t,
            *reinterpret_cast<const uint4*>(&lds[(wmo + t * 16 + li) * 72 + kk + q * 8]));
#pragma unroll
      for (int t = 0; t < 4; ++t)
        wf[t] = __builtin_bit_cast(bf8_t,
            *reinterpret_cast<const uint4*>(&ldsW[(wno + t * 16 + li) * 72 + kk + q * 8]));
#pragma unroll
      for (int i = 0; i < 4; ++i)
#pragma unroll
        for (int j = 0; j < 4; ++j)
          acc[i][j] = __builtin_amdgcn_mfma_f32_16x16x32_bf16(af[i], wf[j], acc[i][j], 0, 0, 0);
    }
  }

  float bias[4];
#pragma unroll
  for (int j = 0; j < 4; ++j) bias[j] = biasCat[g * 128 + wno + j * 16 + li];

  __syncthreads();                               // LDS readers done; reuse as epilogue tile
#pragma unroll
  for (int i = 0; i < 4; ++i)
#pragma unroll
    for (int j = 0; j < 4; ++j)
#pragma unroll
      for (int r2 = 0; r2 < 4; ++r2) {
        int m = wmo + i * 16 + q * 4 + r2;
        int col = wno + j * 16 + li;
        lds[m * TS + col] = f2bf(acc[i][j][r2] + bias[j]);
      }
  __syncthreads();

  // epilogue weights for MODE2 (chunk-invariant: ch = (tid&15)*8 .. +7)
  float wzf[8][3], wzs[8][3];
  if (MODE == 2) {
    int chb = (tid & 15) * 8;
#pragma unroll
    for (int c = 0; c < 8; ++c)
#pragma unroll
      for (int d = 0; d < 3; ++d) {
        wzf[c][d] = Wfo[(chb + c) * 3 + d];
        wzs[c][d] = Wso[(chb + c) * 3 + d];
      }
  }

  // coalesced IO: 2048 uint4 chunks (row = idx>>4, 8-col chunk = idx&15)
#pragma unroll
  for (int p2 = 0; p2 < 8; ++p2) {
    int idx = p2 * 256 + tid;
    int row = idx >> 4, ch = idx & 15;
    uint4 cv = *reinterpret_cast<const uint4*>(&lds[row * TS + ch * 8]);
    size_t gid = (size_t)(m0 + row) * 16 + ch;
    if (MODE == 0) {
      uint4 o;
      o.x = relu2(cv.x); o.y = relu2(cv.y); o.z = relu2(cv.z); o.w = relu2(cv.w);
      ((uint4*)rout)[gid] = o;
    } else if (MODE == 1) {
      uint4 xv = ((const uint4*)xresid)[gid];
      uint4 nx;
      float x0, x1;
      x0 = lo2f(xv.x) + lo2f(cv.x); x1 = hi2f(xv.x) + hi2f(cv.x); nx.x = pack2(x0, x1);
      x0 = lo2f(xv.y) + lo2f(cv.y); x1 = hi2f(xv.y) + hi2f(cv.y); nx.y = pack2(x0, x1);
      x0 = lo2f(xv.z) + lo2f(cv.z); x1 = hi2f(xv.z) + hi2f(cv.z); nx.z = pack2(x0, x1);
      x0 = lo2f(xv.w) + lo2f(cv.w); x1 = hi2f(xv.w) + hi2f(cv.w); nx.w = pack2(x0, x1);
      ((uint4*)xresid)[gid] = nx;
    } else {                                     // MODE 2: fused zproj, no xb write
      uint4 xv = ((const uint4*)xresid)[gid];
      float zf0 = 0.f, zf1 = 0.f, zf2 = 0.f, zs0 = 0.f, zs1 = 0.f, zs2 = 0.f;
#pragma unroll
      for (int q2 = 0; q2 < 4; ++q2) {
        u32 xu = ((const u32*)&xv)[q2], cu = ((const u32*)&cv)[q2];
        float r0 = fmaxf(lo2f(xu) + lo2f(cu), 0.f);
        float r1 = fmaxf(hi2f(xu) + hi2f(cu), 0.f);
        int c = 2 * q2;
        zf0 += r0 * wzf[c][0] + r1 * wzf[c + 1][0];
        zf1 += r0 * wzf[c][1] + r1 * wzf[c + 1][1];
        zf2 += r0 * wzf[c][2] + r1 * wzf[c + 1][2];
        zs0 += r0 * wzs[c][0] + r1 * wzs[c + 1][0];
        zs1 += r0 * wzs[c][1] + r1 * wzs[c + 1][1];
        zs2 += r0 * wzs[c][2] + r1 * wzs[c + 1][2];
      }
#pragma unroll
      for (int off = 1; off < 16; off <<= 1) {
        zf0 += __shfl_xor(zf0, off); zf1 += __shfl_xor(zf1, off); zf2 += __shfl_xor(zf2, off);
        zs0 += __shfl_xor(zs0, off); zs1 += __shfl_xor(zs1, off); zs2 += __shfl_xor(zs2, off);
      }
      if ((tid & 15) == 0) {
        int m = m0 + row;
        zf4[m] = make_float4(zf0, zf1, zf2, 0.f);
        zs4[m] = make_float4(zs0 + bso[0] + bfo[0], zs1 + bso[1] + bfo[1],
                             zs2 + bso[2] + bfo[2], 0.f);
      }
    }
  }
}

// ---------------- 3-channel spmm + add ----------------
__global__ void spmm3_kernel(const int* __restrict__ row_ptr, const int* __restrict__ cols_s,
                             const float4* __restrict__ zf4, const float4* __restrict__ zs4,
                             float* __restrict__ out) {
  int idx = blockIdx.x * 256 + threadIdx.x;
  if (idx >= BN) return;
  int b = (idx >= N_NODES) ? 1 : 0;
  int r = idx - b * N_NODES;
  int s = row_ptr[r], e = row_ptr[r + 1];
  const float4* Z = zf4 + (size_t)b * N_NODES;
  float a0 = 0.f, a1 = 0.f, a2 = 0.f;
  for (int i = s; i < e; ++i) {
    float4 z = Z[cols_s[i]];
    a0 += z.x; a1 += z.y; a2 += z.z;
  }
  float sc = (e > s) ? 1.f / (float)(e - s) : 0.f;
  float4 zs = zs4[idx];
  out[idx * 3 + 0] = zs.x + a0 * sc;
  out[idx * 3 + 1] = zs.y + a1 * sc;
  out[idx * 3 + 2] = zs.z + a2 * sc;
}

extern "C" void kernel_launch(void* const* d_in, const int* in_sizes, int n_in,
                              void* d_out, int out_size, void* d_ws, size_t ws_size,
                              hipStream_t stream) {
  float* out = (float*)d_out;
  int fill_grid = (out_size + 255) / 256;

  const int exp_sizes[14] = {240000, 640000, 640000, 640000, 384, 128,
                             65536, 512, 65536, 512, 384, 3, 384, 3};
  bool sizes_ok = (n_in == 14);
  if (sizes_ok) for (int i = 0; i < 14; ++i) if (in_sizes[i] != exp_sizes[i]) sizes_ok = false;
  if (!sizes_ok) {
    fill_kernel<<<fill_grid, 256, 0, stream>>>(out, out_size, 1.0f);
    return;
  }

  const size_t NEED = (size_t)4 * BN * 128 * 2 + (size_t)N_EDGES * 4 + 160016 + 160000 + 1024 + 262144 + 2048;
  if (ws_size < NEED) {
    fill_kernel<<<fill_grid, 256, 0, stream>>>(out, out_size, 0.0f);
    return;
  }

  const float* p      = (const float*)d_in[0];
  const int*   erows  = (const int*)d_in[2];
  const int*   ecols  = (const int*)d_in[3];
  const float* W_init = (const float*)d_in[4];
  const float* b_init = (const float*)d_in[5];
  const float* Wf_b   = (const float*)d_in[6];
  const float* bf_b   = (const float*)d_in[7];
  const float* Ws_b   = (const float*)d_in[8];
  const float* bs_b   = (const float*)d_in[9];
  const float* Wf_o   = (const float*)d_in[10];
  const float* bf_o   = (const float*)d_in[11];
  const float* Ws_o   = (const float*)d_in[12];
  const float* bs_o   = (const float*)d_in[13];

  char* w = (char*)d_ws;
  char*  zbuf     = w;         w += (size_t)BN * 128 * 2;       // holds zf4/zs4
  u16*   rB       = (u16*)w;   w += (size_t)BN * 128 * 2;
  u16*   y        = (u16*)w;   w += (size_t)BN * 128 * 2;
  u16*   xb       = (u16*)w;   w += (size_t)BN * 128 * 2;
  int*   cols_s   = (int*)w;   w += (size_t)N_EDGES * 4;
  int*   row_ptr  = (int*)w;   w += 160016;
  int*   cnt      = (int*)w;   w += 160000;
  int*   blocksum = (int*)w;   w += 1024;
  u16*   WtCat    = (u16*)w;   w += 4 * 128 * 256 * 2;
  float* biasCat  = (float*)w; w += 4 * 128 * 4;

  float4* zf4 = (float4*)zbuf;                                  // 1,280,000 B
  float4* zs4 = (float4*)(zbuf + 1280000);                      // 1,280,000 B

  const int NBLK = (N_NODES + 255) / 256;                       // 157

  hipMemsetAsync(cnt, 0, N_NODES * 4, stream);
  hist_kernel<<<2500, 256, 0, stream>>>(erows, cnt);
  scan1_kernel<<<NBLK, 256, 0, stream>>>(cnt, row_ptr, blocksum);
  scan2_kernel<<<1, 256, 0, stream>>>(blocksum, row_ptr, NBLK);
  scan3_kernel<<<NBLK, 256, 0, stream>>>(row_ptr, blocksum, cnt);
  scatter_kernel<<<2500, 256, 0, stream>>>(erows, ecols, cnt, cols_s);
  initw_kernel<<<20512, 256, 0, stream>>>(p, W_init, b_init, xb,
                                          Wf_b, Ws_b, bf_b, bs_b, WtCat, biasCat);

  for (int blk = 0; blk < 2; ++blk) {
    spmm_kernel<1><<<10000, 256, 0, stream>>>(row_ptr, cols_s, xb, y);
    gemm_kernel<0><<<625, 256, 0, stream>>>(xb, y, WtCat, biasCat, 2 * blk, rB, nullptr,
                                            nullptr, nullptr, nullptr, nullptr, nullptr, nullptr);
    spmm_kernel<0><<<10000, 256, 0, stream>>>(row_ptr, cols_s, rB, y);
    if (blk == 0)
      gemm_kernel<1><<<625, 256, 0, stream>>>(rB, y, WtCat, biasCat, 1, nullptr, xb,
                                              nullptr, nullptr, nullptr, nullptr, nullptr, nullptr);
    else
      gemm_kernel<2><<<625, 256, 0, stream>>>(rB, y, WtCat, biasCat, 3, nullptr, xb,
                                              zf4, zs4, Wf_o, Ws_o, bf_o, bs_o);
  }
  spmm3_kernel<<<(BN + 255) / 256, 256, 0, stream>>>(row_ptr, cols_s, zf4, zs4, out);
}

// Round 15
// 421.607 us; speedup vs baseline: 1.1322x; 1.0159x over previous
//
#include <hip/hip_runtime.h>

// GCNDecoder: B=2, N=40000, HID=128, E=640000, IN=3, OUT=3. Float tensors f32; indices int32.
//
// Round 15 vs round 14 (428.3 us):
//   - spmm de-templated: spmm_plain = byte-level r9 clone (VGPR-28 codegen target),
//     spmm_relu = same text + fmaxf per term. Isolates the template/inline-fn codegen delta.
//   - hist merged into initw (16 -> 15 dispatches; prep chain is gap-dominated).
//   - gemm/zproj/spmm3 = round-14 (proven).

typedef unsigned short u16;
typedef unsigned int   u32;
typedef __bf16 bf8_t __attribute__((ext_vector_type(8)));
typedef float  f4_t  __attribute__((ext_vector_type(4)));

#define N_NODES 40000
#define N_EDGES 640000
#define BN      80000            // BATCH * N_NODES

__device__ __forceinline__ float bf2f(u16 u) {
  union { u32 i; float f; } v; v.i = ((u32)u) << 16; return v.f;
}
__device__ __forceinline__ u16 f2bf(float f) {
  union { float f; u32 i; } v; v.f = f;
  u32 i = v.i;
  return (u16)((i + 0x7FFFu + ((i >> 16) & 1u)) >> 16);   // RNE
}
__device__ __forceinline__ float asf(u32 i) {
  union { u32 u; float f; } v; v.u = i; return v.f;
}
__device__ __forceinline__ u32 pack2(float a, float b) {
  return (u32)f2bf(a) | ((u32)f2bf(b) << 16);
}
__device__ __forceinline__ float lo2f(u32 v) { return asf(v << 16); }
__device__ __forceinline__ float hi2f(u32 v) { return asf(v & 0xffff0000u); }
__device__ __forceinline__ u32 relu2(u32 v) {     // zero out negative bf16 halves (packed)
  u32 r = v;
  if (r & 0x8000u)     r &= 0xffff0000u;
  if (r & 0x80000000u) r &= 0x0000ffffu;
  return r;
}

__global__ void fill_kernel(float* __restrict__ out, int n, float v) {
  int i = blockIdx.x * 256 + threadIdx.x;
  if (i < n) out[i] = v;
}

// ---------------- CSR scan (3-phase) + scatter ----------------
__global__ void scan1_kernel(const int* __restrict__ cnt, int* __restrict__ row_ptr,
                             int* __restrict__ blocksum) {
  __shared__ int sm[256];
  int t = threadIdx.x;
  int row = blockIdx.x * 256 + t;
  int v = (row < N_NODES) ? cnt[row] : 0;
  sm[t] = v; __syncthreads();
  for (int off = 1; off < 256; off <<= 1) {
    int u = (t >= off) ? sm[t - off] : 0;
    __syncthreads();
    sm[t] += u;
    __syncthreads();
  }
  if (row < N_NODES) row_ptr[row] = sm[t] - v;
  if (t == 255) blocksum[blockIdx.x] = sm[255];
}

__global__ void scan2_kernel(int* __restrict__ blocksum, int* __restrict__ row_ptr, int nblk) {
  __shared__ int sm[256];
  int t = threadIdx.x;
  int v = (t < nblk) ? blocksum[t] : 0;
  sm[t] = v; __syncthreads();
  for (int off = 1; off < 256; off <<= 1) {
    int u = (t >= off) ? sm[t - off] : 0;
    __syncthreads();
    sm[t] += u;
    __syncthreads();
  }
  if (t < nblk) blocksum[t] = sm[t] - v;
  if (t == 255) row_ptr[N_NODES] = sm[255];
}

__global__ void scan3_kernel(int* __restrict__ row_ptr, const int* __restrict__ blocksum,
                             int* __restrict__ cnt) {
  int row = blockIdx.x * 256 + threadIdx.x;
  if (row < N_NODES) {
    int rp = row_ptr[row] + blocksum[blockIdx.x];
    row_ptr[row] = rp;
    cnt[row] = rp;
  }
}

__global__ void scatter_kernel(const int* __restrict__ rows, const int* __restrict__ cols,
                               int* __restrict__ cur, int* __restrict__ cols_s) {
  int e = blockIdx.x * 256 + threadIdx.x;
  if (e < N_EDGES) {
    int r = rows[e];
    int pos = atomicAdd(&cur[r], 1);
    cols_s[pos] = cols[e];
  }
}

// ---------------- merged: xb init (20000) + wprep (512) + hist (2500) ----------------
__global__ void initw_kernel(const float* __restrict__ p, const float* __restrict__ W,
                             const float* __restrict__ bias, u16* __restrict__ xb,
                             const float* __restrict__ Wf_b, const float* __restrict__ Ws_b,
                             const float* __restrict__ bf_b, const float* __restrict__ bs_b,
                             u16* __restrict__ WtCat, float* __restrict__ biasCat,
                             const int* __restrict__ erows, int* __restrict__ cnt) {
  if (blockIdx.x >= 20512) {                     // hist part: 2500 blocks
    int e = (blockIdx.x - 20512) * 256 + threadIdx.x;
    if (e < N_EDGES) atomicAdd(&cnt[erows[e]], 1);
    return;
  }
  if (blockIdx.x >= 20000) {                     // wprep part: 512 blocks
    int idx = (blockIdx.x - 20000) * 256 + threadIdx.x;   // 4*128*256 = 131072
    int g = idx >> 15, rem = idx & 32767;
    int h = rem >> 8, k = rem & 255;
    float v = (k < 128) ? Ws_b[(g * 128 + k) * 128 + h]
                        : Wf_b[(g * 128 + (k - 128)) * 128 + h];
    WtCat[idx] = f2bf(v);
    if (k == 0) biasCat[g * 128 + h] = bs_b[g * 128 + h] + bf_b[g * 128 + h];
    return;
  }
  int idx = blockIdx.x * 256 + threadIdx.x;      // BN*64 = 5,120,000
  int row = idx >> 6;
  int h = (idx & 63) * 2;
  float p0 = p[row * 3], p1 = p[row * 3 + 1], p2 = p[row * 3 + 2];
  float s0 = p0 * W[h]     + p1 * W[128 + h]     + p2 * W[256 + h]     + bias[h];
  float s1 = p0 * W[h + 1] + p1 * W[128 + h + 1] + p2 * W[256 + h + 1] + bias[h + 1];
  ((u32*)xb)[(size_t)row * 64 + (h >> 1)] = pack2(s0, s1);
}

// ---------------- gather SPMM (plain): y[b][r][:] = (1/deg) * sum_e x[b][col[e]][:] ----------------
// Byte-level r9 clone: dual-batch wave, 4 subgroups x 16 lanes, 8-edge main loop.
#define ACC8P(u, a0, a1, a2, a3, a4, a5, a6, a7)                          \
  a0 += asf((u).x << 16); a1 += asf((u).x & 0xffff0000u);                 \
  a2 += asf((u).y << 16); a3 += asf((u).y & 0xffff0000u);                 \
  a4 += asf((u).z << 16); a5 += asf((u).z & 0xffff0000u);                 \
  a6 += asf((u).w << 16); a7 += asf((u).w & 0xffff0000u);

__global__ void spmm_plain(const int* __restrict__ row_ptr, const int* __restrict__ cols_s,
                           const u16* __restrict__ xin, u16* __restrict__ yout) {
  int row = blockIdx.x * 4 + (threadIdx.x >> 6);
  int l = threadIdx.x & 63;
  int g = l >> 4, sl = l & 15;
  int s = row_ptr[row], e = row_ptr[row + 1];
  const uint4* X0 = (const uint4*)xin + sl;
  const uint4* X1 = X0 + 640000;
  float a0 = 0.f, a1 = 0.f, a2 = 0.f, a3 = 0.f, a4 = 0.f, a5 = 0.f, a6 = 0.f, a7 = 0.f;
  float b0 = 0.f, b1 = 0.f, b2 = 0.f, b3 = 0.f, b4 = 0.f, b5 = 0.f, b6 = 0.f, b7 = 0.f;
  int i = s;
  for (; i + 7 < e; i += 8) {
    int c0 = cols_s[i + g], c1 = cols_s[i + 4 + g];
    uint4 u00 = X0[(size_t)c0 * 16];
    uint4 u01 = X1[(size_t)c0 * 16];
    uint4 u10 = X0[(size_t)c1 * 16];
    uint4 u11 = X1[(size_t)c1 * 16];
    ACC8P(u00, a0, a1, a2, a3, a4, a5, a6, a7);
    ACC8P(u01, b0, b1, b2, b3, b4, b5, b6, b7);
    ACC8P(u10, a0, a1, a2, a3, a4, a5, a6, a7);
    ACC8P(u11, b0, b1, b2, b3, b4, b5, b6, b7);
  }
  for (; i + 3 < e; i += 4) {
    int c = cols_s[i + g];
    uint4 u0 = X0[(size_t)c * 16];
    uint4 u1 = X1[(size_t)c * 16];
    ACC8P(u0, a0, a1, a2, a3, a4, a5, a6, a7);
    ACC8P(u1, b0, b1, b2, b3, b4, b5, b6, b7);
  }
  if (i + g < e) {
    int c = cols_s[i + g];
    uint4 u0 = X0[(size_t)c * 16];
    uint4 u1 = X1[(size_t)c * 16];
    ACC8P(u0, a0, a1, a2, a3, a4, a5, a6, a7);
    ACC8P(u1, b0, b1, b2, b3, b4, b5, b6, b7);
  }
  a0 += __shfl_xor(a0, 16); a1 += __shfl_xor(a1, 16); a2 += __shfl_xor(a2, 16); a3 += __shfl_xor(a3, 16);
  a4 += __shfl_xor(a4, 16); a5 += __shfl_xor(a5, 16); a6 += __shfl_xor(a6, 16); a7 += __shfl_xor(a7, 16);
  b0 += __shfl_xor(b0, 16); b1 += __shfl_xor(b1, 16); b2 += __shfl_xor(b2, 16); b3 += __shfl_xor(b3, 16);
  b4 += __shfl_xor(b4, 16); b5 += __shfl_xor(b5, 16); b6 += __shfl_xor(b6, 16); b7 += __shfl_xor(b7, 16);
  a0 += __shfl_xor(a0, 32); a1 += __shfl_xor(a1, 32); a2 += __shfl_xor(a2, 32); a3 += __shfl_xor(a3, 32);
  a4 += __shfl_xor(a4, 32); a5 += __shfl_xor(a5, 32); a6 += __shfl_xor(a6, 32); a7 += __shfl_xor(a7, 32);
  b0 += __shfl_xor(b0, 32); b1 += __shfl_xor(b1, 32); b2 += __shfl_xor(b2, 32); b3 += __shfl_xor(b3, 32);
  b4 += __shfl_xor(b4, 32); b5 += __shfl_xor(b5, 32); b6 += __shfl_xor(b6, 32); b7 += __shfl_xor(b7, 32);
  float sc = (e > s) ? 1.f / (float)(e - s) : 0.f;
  if (g == 0) {
    uint4 o;
    o.x = pack2(a0 * sc, a1 * sc);
    o.y = pack2(a2 * sc, a3 * sc);
    o.z = pack2(a4 * sc, a5 * sc);
    o.w = pack2(a6 * sc, a7 * sc);
    *((uint4*)yout + (size_t)row * 16 + sl) = o;
  } else if (g == 1) {
    uint4 o;
    o.x = pack2(b0 * sc, b1 * sc);
    o.y = pack2(b2 * sc, b3 * sc);
    o.z = pack2(b4 * sc, b5 * sc);
    o.w = pack2(b6 * sc, b7 * sc);
    *((uint4*)yout + 640000 + (size_t)row * 16 + sl) = o;
  }
}

// ---------------- gather SPMM (relu-on-read of xb): same text, fmaxf per term ----------------
#define ACC8M(u, a0, a1, a2, a3, a4, a5, a6, a7)                                        \
  a0 += fmaxf(asf((u).x << 16), 0.f); a1 += fmaxf(asf((u).x & 0xffff0000u), 0.f);       \
  a2 += fmaxf(asf((u).y << 16), 0.f); a3 += fmaxf(asf((u).y & 0xffff0000u), 0.f);       \
  a4 += fmaxf(asf((u).z << 16), 0.f); a5 += fmaxf(asf((u).z & 0xffff0000u), 0.f);       \
  a6 += fmaxf(asf((u).w << 16), 0.f); a7 += fmaxf(asf((u).w & 0xffff0000u), 0.f);

__global__ void spmm_relu(const int* __restrict__ row_ptr, const int* __restrict__ cols_s,
                          const u16* __restrict__ xin, u16* __restrict__ yout) {
  int row = blockIdx.x * 4 + (threadIdx.x >> 6);
  int l = threadIdx.x & 63;
  int g = l >> 4, sl = l & 15;
  int s = row_ptr[row], e = row_ptr[row + 1];
  const uint4* X0 = (const uint4*)xin + sl;
  const uint4* X1 = X0 + 640000;
  float a0 = 0.f, a1 = 0.f, a2 = 0.f, a3 = 0.f, a4 = 0.f, a5 = 0.f, a6 = 0.f, a7 = 0.f;
  float b0 = 0.f, b1 = 0.f, b2 = 0.f, b3 = 0.f, b4 = 0.f, b5 = 0.f, b6 = 0.f, b7 = 0.f;
  int i = s;
  for (; i + 7 < e; i += 8) {
    int c0 = cols_s[i + g], c1 = cols_s[i + 4 + g];
    uint4 u00 = X0[(size_t)c0 * 16];
    uint4 u01 = X1[(size_t)c0 * 16];
    uint4 u10 = X0[(size_t)c1 * 16];
    uint4 u11 = X1[(size_t)c1 * 16];
    ACC8M(u00, a0, a1, a2, a3, a4, a5, a6, a7);
    ACC8M(u01, b0, b1, b2, b3, b4, b5, b6, b7);
    ACC8M(u10, a0, a1, a2, a3, a4, a5, a6, a7);
    ACC8M(u11, b0, b1, b2, b3, b4, b5, b6, b7);
  }
  for (; i + 3 < e; i += 4) {
    int c = cols_s[i + g];
    uint4 u0 = X0[(size_t)c * 16];
    uint4 u1 = X1[(size_t)c * 16];
    ACC8M(u0, a0, a1, a2, a3, a4, a5, a6, a7);
    ACC8M(u1, b0, b1, b2, b3, b4, b5, b6, b7);
  }
  if (i + g < e) {
    int c = cols_s[i + g];
    uint4 u0 = X0[(size_t)c * 16];
    uint4 u1 = X1[(size_t)c * 16];
    ACC8M(u0, a0, a1, a2, a3, a4, a5, a6, a7);
    ACC8M(u1, b0, b1, b2, b3, b4, b5, b6, b7);
  }
  a0 += __shfl_xor(a0, 16); a1 += __shfl_xor(a1, 16); a2 += __shfl_xor(a2, 16); a3 += __shfl_xor(a3, 16);
  a4 += __shfl_xor(a4, 16); a5 += __shfl_xor(a5, 16); a6 += __shfl_xor(a6, 16); a7 += __shfl_xor(a7, 16);
  b0 += __shfl_xor(b0, 16); b1 += __shfl_xor(b1, 16); b2 += __shfl_xor(b2, 16); b3 += __shfl_xor(b3, 16);
  b4 += __shfl_xor(b4, 16); b5 += __shfl_xor(b5, 16); b6 += __shfl_xor(b6, 16); b7 += __shfl_xor(b7, 16);
  a0 += __shfl_xor(a0, 32); a1 += __shfl_xor(a1, 32); a2 += __shfl_xor(a2, 32); a3 += __shfl_xor(a3, 32);
  a4 += __shfl_xor(a4, 32); a5 += __shfl_xor(a5, 32); a6 += __shfl_xor(a6, 32); a7 += __shfl_xor(a7, 32);
  b0 += __shfl_xor(b0, 32); b1 += __shfl_xor(b1, 32); b2 += __shfl_xor(b2, 32); b3 += __shfl_xor(b3, 32);
  b4 += __shfl_xor(b4, 32); b5 += __shfl_xor(b5, 32); b6 += __shfl_xor(b6, 32); b7 += __shfl_xor(b7, 32);
  float sc = (e > s) ? 1.f / (float)(e - s) : 0.f;
  if (g == 0) {
    uint4 o;
    o.x = pack2(a0 * sc, a1 * sc);
    o.y = pack2(a2 * sc, a3 * sc);
    o.z = pack2(a4 * sc, a5 * sc);
    o.w = pack2(a6 * sc, a7 * sc);
    *((uint4*)yout + (size_t)row * 16 + sl) = o;
  } else if (g == 1) {
    uint4 o;
    o.x = pack2(b0 * sc, b1 * sc);
    o.y = pack2(b2 * sc, b3 * sc);
    o.z = pack2(b4 * sc, b5 * sc);
    o.w = pack2(b6 * sc, b7 * sc);
    *((uint4*)yout + 640000 + (size_t)row * 16 + sl) = o;
  }
}

// ---------------- fused gconv GEMM: [fin(rin) | y] (M x 256) @ WtCat[g]^T (256 x 128) + bias ----
// Round-14 exact body: A and W staged in LDS, single-pass TS=136 epilogue.
// MODE 0: A-half = relu(rin) in staging; rout = relu(acc+bias)                 (rin = xb)
// MODE 1: A-half = rin as-is (rB); xb += acc+bias, write xb only
// MODE 2: MODE 1 + fused zproj (zf/zs from fp32 xb+dx), NO xb write (dead after)
#define TS 136                                   // tile row stride (u16); 272 B, 16B-aligned
template <int MODE>
__global__ __launch_bounds__(256, 4) void gemm_kernel(
    const u16* __restrict__ rin, const u16* __restrict__ yin,
    const u16* __restrict__ WtCat, const float* __restrict__ biasCat, int g,
    u16* __restrict__ rout, u16* __restrict__ xresid,
    float4* __restrict__ zf4, float4* __restrict__ zs4,
    const float* __restrict__ Wfo, const float* __restrict__ Wso,
    const float* __restrict__ bfo, const float* __restrict__ bso) {
  __shared__ __align__(16) u16 lds[18432];       // 36,864 B: ldsA[0..9215], ldsW[9216..]; epi tile 128*TS
  u16* ldsW = lds + 9216;
  int tid = threadIdx.x;
  int m0 = blockIdx.x * 128;
  int li = tid & 15, q = (tid >> 4) & 3, wv = tid >> 6;
  int wmo = (wv >> 1) * 64, wno = (wv & 1) * 64;

  f4_t acc[4][4];
#pragma unroll
  for (int i = 0; i < 4; ++i)
#pragma unroll
    for (int j = 0; j < 4; ++j) acc[i][j] = (f4_t){0.f, 0.f, 0.f, 0.f};

  const u16* Wsrc = WtCat + (size_t)g * 32768;

  for (int kb = 0; kb < 256; kb += 64) {
    __syncthreads();
    const u16* srcA = (kb < 128) ? (rin + kb) : (yin + (kb - 128));
#pragma unroll
    for (int p2 = 0; p2 < 4; ++p2) {
      int idx = p2 * 256 + tid;                  // 0..1023
      int row = idx >> 3, seg = idx & 7;
      uint4 va = *reinterpret_cast<const uint4*>(srcA + (size_t)(m0 + row) * 128 + seg * 8);
      if (MODE == 0 && kb < 128) {               // relu-on-read of xb
        va.x = relu2(va.x); va.y = relu2(va.y); va.z = relu2(va.z); va.w = relu2(va.w);
      }
      *reinterpret_cast<uint4*>(&lds[row * 72 + seg * 8]) = va;
      uint4 vw = *reinterpret_cast<const uint4*>(Wsrc + (size_t)row * 256 + kb + seg * 8);
      *reinterpret_cast<uint4*>(&ldsW[row * 72 + seg * 8]) = vw;
    }
    __syncthreads();
#pragma unroll
    for (int kk = 0; kk < 64; kk += 32) {
      bf8_t af[4], wf[4];
#pragma unroll
      for (int t = 0; t < 4; ++t)
        af[t] = __builtin_bit_cast(bf8_t,
            *reinterpret_cast<const uint4*>(&lds[(wmo + t * 16 + li) * 72 + kk + q * 8]));
#pragma unroll
      for (int t = 0; t < 4; ++t)
        wf[t] = __builtin_bit_cast(bf8_t,
            *reinterpret_cast<const uint4*>(&ldsW[(wno + t * 16 + li) * 72 + kk + q * 8]));
#pragma unroll
      for (int i = 0; i < 4; ++i)
#pragma unroll
        for (int j = 0; j < 4; ++j)
          acc[i][j] = __builtin_amdgcn_mfma_f32_16x16x32_bf16(af[i], wf[j], acc[i][j], 0, 0, 0);
    }
  }

  float bias[4];
#pragma unroll
  for (int j = 0; j < 4; ++j) bias[j] = biasCat[g * 128 + wno + j * 16 + li];

  __syncthreads();                               // LDS readers done; reuse as epilogue tile
#pragma unroll
  for (int i = 0; i < 4; ++i)
#pragma unroll
    for (int j = 0; j < 4; ++j)
#pragma unroll
      for (int r2 = 0; r2 < 4; ++r2) {
        int m = wmo + i * 16 + q * 4 + r2;
        int col = wno + j * 16 + li;
        lds[m * TS + col] = f2bf(acc[i][j][r2] + bias[j]);
      }
  __syncthreads();

  // epilogue weights for MODE2 (chunk-invariant: ch = (tid&15)*8 .. +7)
  float wzf[8][3], wzs[8][3];
  if (MODE == 2) {
    int chb = (tid & 15) * 8;
#pragma unroll
    for (int c = 0; c < 8; ++c)
#pragma unroll
      for (int d = 0; d < 3; ++d) {
        wzf[c][d] = Wfo[(chb + c) * 3 + d];
        wzs[c][d] = Wso[(chb + c) * 3 + d];
      }
  }

  // coalesced IO: 2048 uint4 chunks (row = idx>>4, 8-col chunk = idx&15)
#pragma unroll
  for (int p2 = 0; p2 < 8; ++p2) {
    int idx = p2 * 256 + tid;
    int row = idx >> 4, ch = idx & 15;
    uint4 cv = *reinterpret_cast<const uint4*>(&lds[row * TS + ch * 8]);
    size_t gid = (size_t)(m0 + row) * 16 + ch;
    if (MODE == 0) {
      uint4 o;
      o.x = relu2(cv.x); o.y = relu2(cv.y); o.z = relu2(cv.z); o.w = relu2(cv.w);
      ((uint4*)rout)[gid] = o;
    } else if (MODE == 1) {
      uint4 xv = ((const uint4*)xresid)[gid];
      uint4 nx;
      float x0, x1;
      x0 = lo2f(xv.x) + lo2f(cv.x); x1 = hi2f(xv.x) + hi2f(cv.x); nx.x = pack2(x0, x1);
      x0 = lo2f(xv.y) + lo2f(cv.y); x1 = hi2f(xv.y) + hi2f(cv.y); nx.y = pack2(x0, x1);
      x0 = lo2f(xv.z) + lo2f(cv.z); x1 = hi2f(xv.z) + hi2f(cv.z); nx.z = pack2(x0, x1);
      x0 = lo2f(xv.w) + lo2f(cv.w); x1 = hi2f(xv.w) + hi2f(cv.w); nx.w = pack2(x0, x1);
      ((uint4*)xresid)[gid] = nx;
    } else {                                     // MODE 2: fused zproj, no xb write
      uint4 xv = ((const uint4*)xresid)[gid];
      float zf0 = 0.f, zf1 = 0.f, zf2 = 0.f, zs0 = 0.f, zs1 = 0.f, zs2 = 0.f;
#pragma unroll
      for (int q2 = 0; q2 < 4; ++q2) {
        u32 xu = ((const u32*)&xv)[q2], cu = ((const u32*)&cv)[q2];
        float r0 = fmaxf(lo2f(xu) + lo2f(cu), 0.f);
        float r1 = fmaxf(hi2f(xu) + hi2f(cu), 0.f);
        int c = 2 * q2;
        zf0 += r0 * wzf[c][0] + r1 * wzf[c + 1][0];
        zf1 += r0 * wzf[c][1] + r1 * wzf[c + 1][1];
        zf2 += r0 * wzf[c][2] + r1 * wzf[c + 1][2];
        zs0 += r0 * wzs[c][0] + r1 * wzs[c + 1][0];
        zs1 += r0 * wzs[c][1] + r1 * wzs[c + 1][1];
        zs2 += r0 * wzs[c][2] + r1 * wzs[c + 1][2];
      }
#pragma unroll
      for (int off = 1; off < 16; off <<= 1) {
        zf0 += __shfl_xor(zf0, off); zf1 += __shfl_xor(zf1, off); zf2 += __shfl_xor(zf2, off);
        zs0 += __shfl_xor(zs0, off); zs1 += __shfl_xor(zs1, off); zs2 += __shfl_xor(zs2, off);
      }
      if ((tid & 15) == 0) {
        int m = m0 + row;
        zf4[m] = make_float4(zf0, zf1, zf2, 0.f);
        zs4[m] = make_float4(zs0 + bso[0] + bfo[0], zs1 + bso[1] + bfo[1],
                             zs2 + bso[2] + bfo[2], 0.f);
      }
    }
  }
}

// ---------------- 3-channel spmm + add ----------------
__global__ void spmm3_kernel(const int* __restrict__ row_ptr, const int* __restrict__ cols_s,
                             const float4* __restrict__ zf4, const float4* __restrict__ zs4,
                             float* __restrict__ out) {
  int idx = blockIdx.x * 256 + threadIdx.x;
  if (idx >= BN) return;
  int b = (idx >= N_NODES) ? 1 : 0;
  int r = idx - b * N_NODES;
  int s = row_ptr[r], e = row_ptr[r + 1];
  const float4* Z = zf4 + (size_t)b * N_NODES;
  float a0 = 0.f, a1 = 0.f, a2 = 0.f;
  for (int i = s; i < e; ++i) {
    float4 z = Z[cols_s[i]];
    a0 += z.x; a1 += z.y; a2 += z.z;
  }
  float sc = (e > s) ? 1.f / (float)(e - s) : 0.f;
  float4 zs = zs4[idx];
  out[idx * 3 + 0] = zs.x + a0 * sc;
  out[idx * 3 + 1] = zs.y + a1 * sc;
  out[idx * 3 + 2] = zs.z + a2 * sc;
}

extern "C" void kernel_launch(void* const* d_in, const int* in_sizes, int n_in,
                              void* d_out, int out_size, void* d_ws, size_t ws_size,
                              hipStream_t stream) {
  float* out = (float*)d_out;
  int fill_grid = (out_size + 255) / 256;

  const int exp_sizes[14] = {240000, 640000, 640000, 640000, 384, 128,
                             65536, 512, 65536, 512, 384, 3, 384, 3};
  bool sizes_ok = (n_in == 14);
  if (sizes_ok) for (int i = 0; i < 14; ++i) if (in_sizes[i] != exp_sizes[i]) sizes_ok = false;
  if (!sizes_ok) {
    fill_kernel<<<fill_grid, 256, 0, stream>>>(out, out_size, 1.0f);
    return;
  }

  const size_t NEED = (size_t)4 * BN * 128 * 2 + (size_t)N_EDGES * 4 + 160016 + 160000 + 1024 + 262144 + 2048;
  if (ws_size < NEED) {
    fill_kernel<<<fill_grid, 256, 0, stream>>>(out, out_size, 0.0f);
    return;
  }

  const float* p      = (const float*)d_in[0];
  const int*   erows  = (const int*)d_in[2];
  const int*   ecols  = (const int*)d_in[3];
  const float* W_init = (const float*)d_in[4];
  const float* b_init = (const float*)d_in[5];
  const float* Wf_b   = (const float*)d_in[6];
  const float* bf_b   = (const float*)d_in[7];
  const float* Ws_b   = (const float*)d_in[8];
  const float* bs_b   = (const float*)d_in[9];
  const float* Wf_o   = (const float*)d_in[10];
  const float* bf_o   = (const float*)d_in[11];
  const float* Ws_o   = (const float*)d_in[12];
  const float* bs_o   = (const float*)d_in[13];

  char* w = (char*)d_ws;
  char*  zbuf     = w;         w += (size_t)BN * 128 * 2;       // holds zf4/zs4
  u16*   rB       = (u16*)w;   w += (size_t)BN * 128 * 2;
  u16*   y        = (u16*)w;   w += (size_t)BN * 128 * 2;
  u16*   xb       = (u16*)w;   w += (size_t)BN * 128 * 2;
  int*   cols_s   = (int*)w;   w += (size_t)N_EDGES * 4;
  int*   row_ptr  = (int*)w;   w += 160016;
  int*   cnt      = (int*)w;   w += 160000;
  int*   blocksum = (int*)w;   w += 1024;
  u16*   WtCat    = (u16*)w;   w += 4 * 128 * 256 * 2;
  float* biasCat  = (float*)w; w += 4 * 128 * 4;

  float4* zf4 = (float4*)zbuf;                                  // 1,280,000 B
  float4* zs4 = (float4*)(zbuf + 1280000);                      // 1,280,000 B

  const int NBLK = (N_NODES + 255) / 256;                       // 157

  hipMemsetAsync(cnt, 0, N_NODES * 4, stream);
  initw_kernel<<<23012, 256, 0, stream>>>(p, W_init, b_init, xb,
                                          Wf_b, Ws_b, bf_b, bs_b, WtCat, biasCat,
                                          erows, cnt);
  scan1_kernel<<<NBLK, 256, 0, stream>>>(cnt, row_ptr, blocksum);
  scan2_kernel<<<1, 256, 0, stream>>>(blocksum, row_ptr, NBLK);
  scan3_kernel<<<NBLK, 256, 0, stream>>>(row_ptr, blocksum, cnt);
  scatter_kernel<<<2500, 256, 0, stream>>>(erows, ecols, cnt, cols_s);

  for (int blk = 0; blk < 2; ++blk) {
    spmm_relu<<<10000, 256, 0, stream>>>(row_ptr, cols_s, xb, y);
    gemm_kernel<0><<<625, 256, 0, stream>>>(xb, y, WtCat, biasCat, 2 * blk, rB, nullptr,
                                            nullptr, nullptr, nullptr, nullptr, nullptr, nullptr);
    spmm_plain<<<10000, 256, 0, stream>>>(row_ptr, cols_s, rB, y);
    if (blk == 0)
      gemm_kernel<1><<<625, 256, 0, stream>>>(rB, y, WtCat, biasCat, 1, nullptr, xb,
                                              nullptr, nullptr, nullptr, nullptr, nullptr, nullptr);
    else
      gemm_kernel<2><<<625, 256, 0, stream>>>(rB, y, WtCat, biasCat, 3, nullptr, xb,
                                              zf4, zs4, Wf_o, Ws_o, bf_o, bs_o);
  }
  spmm3_kernel<<<(BN + 255) / 256, 256, 0, stream>>>(row_ptr, cols_s, zf4, zs4, out);
}